// Round 7
// baseline (598.709 us; speedup 1.0000x reference)
//
#include <hip/hip_runtime.h>
#include <cstdint>

constexpr int NB   = 8;
constexpr int LQn  = 900;
constexpr int CD   = 256;
constexpr int LENS = 21760;
constexpr int NQ   = NB * LQn;    // 7200
constexpr int NV   = NB * LENS;   // 174080

using short8 = __attribute__((ext_vector_type(8))) short;
using f32x4  = __attribute__((ext_vector_type(4))) float;

__device__ __forceinline__ ushort f2b(float x) {
    uint32_t u = __builtin_bit_cast(uint32_t, x);
    u += 0x7fffu + ((u >> 16) & 1u);
    return (ushort)(u >> 16);
}
__device__ __forceinline__ float b2f(ushort x) {
    uint32_t u = ((uint32_t)x) << 16;
    return __builtin_bit_cast(float, u);
}
__device__ __forceinline__ float b2f_lo(uint32_t u) {
    return __builtin_bit_cast(float, u << 16);
}
__device__ __forceinline__ float b2f_hi(uint32_t u) {
    return __builtin_bit_cast(float, u & 0xffff0000u);
}
// hardware packed f32x2 -> bf16x2 (RNE), gfx950: lo->bits[15:0], hi->bits[31:16]
__device__ __forceinline__ uint32_t cvtpk(float lo, float hi) {
    uint32_t r;
    asm("v_cvt_pk_bf16_f32 %0, %1, %2" : "=v"(r) : "v"(lo), "v"(hi));
    return r;
}

// ---------------------------------------------------------------------------
// Weight conversion + bias concat for the fused off/aw projection.
// ---------------------------------------------------------------------------
struct WPtrs { const float* p[8]; };
__constant__ const int kWOff[9] = {0, 196608, 262144, 327680, 360448, 425984,
                                   491520, 753664, 1015808};

__global__ __launch_bounds__(256) void cvt_w_kernel(
    WPtrs w, ushort* __restrict__ out,
    const float* __restrict__ offb, const float* __restrict__ awb,
    float* __restrict__ biascat)
{
    if (blockIdx.x == 992) {
        for (int t = threadIdx.x; t < 384; t += 256)
            biascat[t] = t < 256 ? offb[t] : awb[t - 256];
        return;
    }
    int i = blockIdx.x * blockDim.x + threadIdx.x;
    int e = i * 4;
    int s = 0;
#pragma unroll
    for (int k = 1; k < 8; ++k) if (e >= kWOff[k]) s = k;
    float4 v = *reinterpret_cast<const float4*>(w.p[s] + (e - kWOff[s]));
    ushort4 o;
    o.x = f2b(v.x); o.y = f2b(v.y); o.z = f2b(v.z); o.w = f2b(v.w);
    *reinterpret_cast<ushort4*>(out + e) = o;
}

__global__ __launch_bounds__(256) void cvt_pair_kernel(
    const float* __restrict__ a, const float* __restrict__ b,
    ushort* __restrict__ sum_bf, ushort* __restrict__ a_bf, int n4) {
    int i = blockIdx.x * blockDim.x + threadIdx.x;
    if (i >= n4) return;
    float4 va = reinterpret_cast<const float4*>(a)[i];
    float4 vb = reinterpret_cast<const float4*>(b)[i];
    ushort4 s, t;
    s.x = f2b(va.x + vb.x); s.y = f2b(va.y + vb.y);
    s.z = f2b(va.z + vb.z); s.w = f2b(va.w + vb.w);
    reinterpret_cast<ushort4*>(sum_bf)[i] = s;
    t.x = f2b(va.x); t.y = f2b(va.y); t.z = f2b(va.z); t.w = f2b(va.w);
    reinterpret_cast<ushort4*>(a_bf)[i] = t;
}

// ---------------------------------------------------------------------------
// Pure streaming f32 -> bf16 convert (HBM diagnostic: copy-pattern).
// Each thread: 8 f32 in, 8 bf16 out per iteration.
// ---------------------------------------------------------------------------
__global__ __launch_bounds__(256) void cvt_src_kernel(
    const float* __restrict__ s, ushort* __restrict__ d, int n8)
{
    int stride = gridDim.x * blockDim.x;
    for (int i = blockIdx.x * blockDim.x + threadIdx.x; i < n8; i += stride) {
        float4 v0 = reinterpret_cast<const float4*>(s)[(size_t)i * 2];
        float4 v1 = reinterpret_cast<const float4*>(s)[(size_t)i * 2 + 1];
        uint4 pk;
        pk.x = cvtpk(v0.x, v0.y);
        pk.y = cvtpk(v0.z, v0.w);
        pk.z = cvtpk(v1.x, v1.y);
        pk.w = cvtpk(v1.z, v1.w);
        reinterpret_cast<uint4*>(d)[i] = pk;
    }
}

// ---------------------------------------------------------------------------
// MFMA GEMM, 2-phase double-buffered: C[M x N] = A[M x K] * B[N x K]^T + bias.
// BM x 128 tile, BK=32, 4 waves (2x2). OUTK: 0=f32, 1=bf16, 2=bf16 val-transposed.
// XCD-bijective swizzle when nwg % 8 == 0 (T1). Optional second A pointer:
// blocks with bx >= xsplit read Av2 (QKV fusion; same M).
// ---------------------------------------------------------------------------
template<int BM, bool A_F32, int OUTK, bool RELU, bool MASK>
__global__ __launch_bounds__(256) void gemm_mfma(
    const void* __restrict__ Av, const void* __restrict__ Av2, int xsplit,
    const ushort* __restrict__ B,
    const float* __restrict__ bias, void* __restrict__ Cv,
    int M, int K, int ldc, const unsigned char* __restrict__ rowmask)
{
    constexpr int RIT = BM / 64;   // A staging iterations
    constexpr int FR  = BM / 32;   // M frags per wave
    __shared__ ushort As[2][BM * 32];
    __shared__ ushort Bs[2][4096];

    // ---- XCD-aware block remap (bijective when nwg % 8 == 0) ----
    int bx, by;
    {
        const int nx = gridDim.x;
        const int nwg = nx * gridDim.y;
        int orig = blockIdx.y * nx + blockIdx.x;
        int wg = orig;
        if ((nwg & 7) == 0 && nwg >= 64)
            wg = (orig & 7) * (nwg >> 3) + (orig >> 3);
        bx = wg % nx; by = wg / nx;
    }

    const int tid = threadIdx.x, lane = tid & 63, wave = tid >> 6;
    const int wr = wave >> 1, wc = wave & 1;
    const int bn = bx * 128;
    const int bm = by * BM;
    const int lc15 = lane & 15, lk = lane >> 4;

    const void* Asel = (Av2 != nullptr && bx >= xsplit) ? Av2 : Av;
    const ushort* Abf = (const ushort*)Asel;
    const float*  Afp = (const float*)Asel;

    f32x4 acc[FR][4] = {};

    int a_off[FR], b_off[4];
#pragma unroll
    for (int fr = 0; fr < FR; ++fr) {
        int r = wr * (BM / 2) + fr * 16 + lc15;
        a_off[fr] = r * 32 + ((lk ^ ((r >> 1) & 3)) * 8);
    }
#pragma unroll
    for (int fc = 0; fc < 4; ++fc) {
        int rb = wc * 64 + fc * 16 + lc15;
        b_off[fc] = rb * 32 + ((lk ^ ((rb >> 1) & 3)) * 8);
    }

    float4 pa0[RIT], pa1[RIT];   // A_F32 in-flight registers

    auto loadA_regs = [&](int k0) {
#pragma unroll
        for (int t = 0; t < RIT; ++t) {
            int s = tid + t * 256;
            int row = s >> 2, p = s & 3;
            int g = p ^ ((row >> 1) & 3);
            size_t ar = (size_t)bm + row; if (ar >= (size_t)M) ar = M - 1;
            const float* gp = Afp + ar * (size_t)K + k0 + g * 8;
            pa0[t] = *reinterpret_cast<const float4*>(gp);
            pa1[t] = *reinterpret_cast<const float4*>(gp + 4);
        }
    };
    auto writeA_lds = [&](int buf) {
#pragma unroll
        for (int t = 0; t < RIT; ++t) {
            int s = tid + t * 256;
            int row = s >> 2, p = s & 3;
            uint4 pk;
            pk.x = cvtpk(pa0[t].x, pa0[t].y);
            pk.y = cvtpk(pa0[t].z, pa0[t].w);
            pk.z = cvtpk(pa1[t].x, pa1[t].y);
            pk.w = cvtpk(pa1[t].z, pa1[t].w);
            *reinterpret_cast<uint4*>(&As[buf][row * 32 + p * 8]) = pk;
        }
    };
    auto stageA_lds = [&](int buf, int k0) {
#pragma unroll
        for (int t = 0; t < RIT; ++t) {
            int row = wave * (16 * RIT) + t * 16 + (lane >> 2);
            int p = lane & 3;
            int g = p ^ ((row >> 1) & 3);
            size_t ar = (size_t)bm + row; if (ar >= (size_t)M) ar = M - 1;
            const ushort* gp = Abf + ar * (size_t)K + k0 + g * 8;
            __builtin_amdgcn_global_load_lds(
                (const __attribute__((address_space(1))) uint32_t*)gp,
                (__attribute__((address_space(3))) uint32_t*)(&As[buf][(wave * RIT + t) * 512]),
                16, 0, 0);
        }
    };
    auto stageB = [&](int buf, int k0) {
#pragma unroll
        for (int t = 0; t < 2; ++t) {
            int row = wave * 32 + t * 16 + (lane >> 2);
            int p = lane & 3;
            int g = p ^ ((row >> 1) & 3);
            const ushort* gp = B + (size_t)(bn + row) * K + k0 + g * 8;
            __builtin_amdgcn_global_load_lds(
                (const __attribute__((address_space(1))) uint32_t*)gp,
                (__attribute__((address_space(3))) uint32_t*)(&Bs[buf][(wave * 2 + t) * 512]),
                16, 0, 0);
        }
    };

    // ---- prologue: fill buffer 0 ----
    if constexpr (A_F32) { loadA_regs(0); writeA_lds(0); }
    else stageA_lds(0, 0);
    stageB(0, 0);
    __syncthreads();

    const int nt = K >> 5;
    int cur = 0;
    for (int t = 0; t < nt; ++t) {
        const int k0n = (t + 1) << 5;
        const bool more = (t + 1 < nt);
        if constexpr (A_F32) {
            if (more) loadA_regs(k0n);
        } else {
            if (more) stageA_lds(cur ^ 1, k0n);
        }
        if (more) stageB(cur ^ 1, k0n);

        short8 af[FR], bfr[4];
#pragma unroll
        for (int fr = 0; fr < FR; ++fr) af[fr]  = *reinterpret_cast<const short8*>(&As[cur][a_off[fr]]);
#pragma unroll
        for (int fc = 0; fc < 4; ++fc) bfr[fc] = *reinterpret_cast<const short8*>(&Bs[cur][b_off[fc]]);
#pragma unroll
        for (int fr = 0; fr < FR; ++fr)
#pragma unroll
            for (int fc = 0; fc < 4; ++fc)
                acc[fr][fc] = __builtin_amdgcn_mfma_f32_16x16x32_bf16(
                    af[fr], bfr[fc], acc[fr][fc], 0, 0, 0);

        if constexpr (A_F32) {
            if (more) writeA_lds(cur ^ 1);
        }
        __syncthreads();
        cur ^= 1;
    }

    // ---- epilogue ----
#pragma unroll
    for (int fc = 0; fc < 4; ++fc) {
        int col = bn + wc * 64 + fc * 16 + lc15;
        float bv = bias[col];
#pragma unroll
        for (int fr = 0; fr < FR; ++fr) {
            int rb = bm + wr * (BM / 2) + fr * 16 + lk * 4;
#pragma unroll
            for (int r = 0; r < 4; ++r) {
                int row = rb + r;
                if (row < M) {
                    float v = acc[fr][fc][r] + bv;
                    if constexpr (RELU) v = fmaxf(v, 0.f);
                    if constexpr (MASK) { if (rowmask[row]) v = 0.f; }
                    if constexpr (OUTK == 0)
                        ((float*)Cv)[(size_t)row * ldc + col] = v;
                    else if constexpr (OUTK == 1)
                        ((ushort*)Cv)[(size_t)row * ldc + col] = f2b(v);
                    else {
                        int brow = row / LENS;
                        int len  = row - brow * LENS;
                        int hh = col >> 5, ch = col & 31;
                        ((ushort*)Cv)[((size_t)(brow * 8 + hh) * LENS + len) * 32 + ch] = f2b(v);
                    }
                }
            }
        }
    }
}

// ---------------------------------------------------------------------------
// MFMA flash self-attention, pipelined: V double-buffered in LDS, K prefetched
// in registers; one barrier per K/V tile. Block = (64-q tile, h, b), 4 waves.
// ---------------------------------------------------------------------------
__global__ __launch_bounds__(256) void attn_mfma(
    const ushort* __restrict__ qkv, ushort* __restrict__ out)
{
    __shared__ ushort Vt[2][32][72];     // [buf][dh][key]
    __shared__ ushort Plds[4][16][72];   // per-wave P [q][key]

    const int tid = threadIdx.x, lane = tid & 63, wave = tid >> 6;
    const int lq = lane & 15, lg = lane >> 4;
    const int q0 = blockIdx.x * 64;
    const int h = blockIdx.y, b = blockIdx.z;
    const size_t bbase = (size_t)b * LQn * 768;

    int qrow = q0 + wave * 16 + lq; if (qrow > LQn - 1) qrow = LQn - 1;
    short8 aq = *reinterpret_cast<const short8*>(
        qkv + bbase + (size_t)qrow * 768 + h * 32 + lg * 8);

    const int vkey = tid >> 2, vdhc = (tid & 3) * 8;

    auto loadV = [&](int kb) {
        int kg = kb + vkey; if (kg > LQn - 1) kg = LQn - 1;
        return *reinterpret_cast<const short8*>(
            qkv + bbase + (size_t)kg * 768 + 512 + h * 32 + vdhc);
    };
    auto loadK = [&](int kb, short8* bk) {
#pragma unroll
        for (int fc = 0; fc < 4; ++fc) {
            int krow = kb + fc * 16 + lq;
            int kc = krow > LQn - 1 ? LQn - 1 : krow;
            bk[fc] = *reinterpret_cast<const short8*>(
                qkv + bbase + (size_t)kc * 768 + 256 + h * 32 + lg * 8);
        }
    };

    f32x4 accO[2] = {};
    float m[4], l[4];
#pragma unroll
    for (int r = 0; r < 4; ++r) { m[r] = -3.0e38f; l[r] = 0.f; }

    short8 vreg = loadV(0);
    short8 kreg[4]; loadK(0, kreg);

    int cur = 0;
    for (int kt = 0; kt < 15; ++kt) {
        const int kb = kt * 64;
#pragma unroll
        for (int j = 0; j < 8; ++j) Vt[cur][vdhc + j][vkey] = (ushort)vreg[j];
        __syncthreads();

        f32x4 s4[4];
#pragma unroll
        for (int fc = 0; fc < 4; ++fc) {
            f32x4 z = {};
            s4[fc] = __builtin_amdgcn_mfma_f32_16x16x32_bf16(aq, kreg[fc], z, 0, 0, 0);
        }
        if (kt + 1 < 15) { vreg = loadV(kb + 64); loadK(kb + 64, kreg); }

#pragma unroll
        for (int fc = 0; fc < 4; ++fc) {
            int krow = kb + fc * 16 + lq;
            bool inval = krow >= LQn;
#pragma unroll
            for (int r = 0; r < 4; ++r)
                s4[fc][r] = inval ? -3.0e38f : s4[fc][r] * 0.17677669529663687f;
        }

#pragma unroll
        for (int r = 0; r < 4; ++r) {
            float rm = fmaxf(fmaxf(s4[0][r], s4[1][r]), fmaxf(s4[2][r], s4[3][r]));
            rm = fmaxf(rm, __shfl_xor(rm, 1));
            rm = fmaxf(rm, __shfl_xor(rm, 2));
            rm = fmaxf(rm, __shfl_xor(rm, 4));
            rm = fmaxf(rm, __shfl_xor(rm, 8));
            float mn = fmaxf(m[r], rm);
            float esc = __expf(m[r] - mn);
            float rs = 0.f;
#pragma unroll
            for (int fc = 0; fc < 4; ++fc) {
                float p = __expf(s4[fc][r] - mn);
                s4[fc][r] = p; rs += p;
            }
            rs += __shfl_xor(rs, 1); rs += __shfl_xor(rs, 2);
            rs += __shfl_xor(rs, 4); rs += __shfl_xor(rs, 8);
            m[r] = mn;
            l[r] = l[r] * esc + rs;
            accO[0][r] *= esc; accO[1][r] *= esc;
        }

#pragma unroll
        for (int fc = 0; fc < 4; ++fc)
#pragma unroll
            for (int r = 0; r < 4; ++r)
                Plds[wave][lg * 4 + r][fc * 16 + lq] = f2b(s4[fc][r]);

#pragma unroll
        for (int ks = 0; ks < 2; ++ks) {
            short8 ap = *reinterpret_cast<const short8*>(&Plds[wave][lq][ks * 32 + lg * 8]);
#pragma unroll
            for (int fc = 0; fc < 2; ++fc) {
                short8 bv = *reinterpret_cast<const short8*>(&Vt[cur][fc * 16 + lq][ks * 32 + lg * 8]);
                accO[fc] = __builtin_amdgcn_mfma_f32_16x16x32_bf16(ap, bv, accO[fc], 0, 0, 0);
            }
        }
        cur ^= 1;
    }

#pragma unroll
    for (int r = 0; r < 4; ++r) {
        int q = q0 + wave * 16 + lg * 4 + r;
        if (q < LQn) {
            float invl = 1.f / l[r];
#pragma unroll
            for (int fc = 0; fc < 2; ++fc)
                out[((size_t)b * LQn + q) * 256 + h * 32 + fc * 16 + lq] =
                    f2b(accO[fc][r] * invl);
        }
    }
}

// ---------------------------------------------------------------------------
// Deformable sampling v2: value in (b, h, LENS, 32) layout; 16 lanes per
// (bq,h) group, 2 channels/lane; params computed by lane=sample, staged in LDS.
// ---------------------------------------------------------------------------
__global__ __launch_bounds__(256) void deform2_kernel(
    const ushort* __restrict__ valt,   // (NB*8, LENS, 32) bf16
    const float* __restrict__ offaw,   // (NQ, 384): [0:256) off, [256:384) aw
    const float* __restrict__ ref,     // (NB, LQ, NL, 2)
    ushort* __restrict__ out)          // (NQ, 256) bf16
{
    __shared__ int   Pi[16][16][4];
    __shared__ float Pw[16][16][4];

    const int tid = threadIdx.x;
    const int grp = tid >> 4;
    const int lane = tid & 15;
    const int gg = blockIdx.x * 16 + grp;
    const int h  = gg / 7200;
    const int bq = gg - h * 7200;
    const int b  = bq / LQn;

    const float* row = offaw + (size_t)bq * 384;
    float aval = row[256 + h * 16 + lane];
    float mx = aval;
    mx = fmaxf(mx, __shfl_xor(mx, 1));
    mx = fmaxf(mx, __shfl_xor(mx, 2));
    mx = fmaxf(mx, __shfl_xor(mx, 4));
    mx = fmaxf(mx, __shfl_xor(mx, 8));
    float e = __expf(aval - mx);
    float se = e;
    se += __shfl_xor(se, 1); se += __shfl_xor(se, 2);
    se += __shfl_xor(se, 4); se += __shfl_xor(se, 8);
    float a = e / se;

    const int lv = lane >> 2;
    const int W = 128 >> lv;
    const int STl[4] = {0, 16384, 20480, 21504};
    const float Wf = (float)W;
    float2 off2 = *reinterpret_cast<const float2*>(row + h * 32 + lane * 2);
    float rx = ref[(size_t)bq * 8 + lv * 2];
    float ry = ref[(size_t)bq * 8 + lv * 2 + 1];
    float x = (rx + off2.x / Wf) * Wf - 0.5f;
    float y = (ry + off2.y / Wf) * Wf - 0.5f;
    float x0f = floorf(x), y0f = floorf(y);
    int x0 = (int)x0f, y0 = (int)y0f;
    float wx = x - x0f, wy = y - y0f;
    float vx0 = (x0 >= 0 && x0 < W) ? 1.f : 0.f;
    float vx1 = (x0 + 1 >= 0 && x0 + 1 < W) ? 1.f : 0.f;
    float vy0 = (y0 >= 0 && y0 < W) ? 1.f : 0.f;
    float vy1 = (y0 + 1 >= 0 && y0 + 1 < W) ? 1.f : 0.f;
    int x0c = min(max(x0, 0), W - 1), x1c = min(max(x0 + 1, 0), W - 1);
    int y0c = min(max(y0, 0), W - 1), y1c = min(max(y0 + 1, 0), W - 1);
    int base = STl[lv];
    Pi[grp][lane][0] = base + y0c * W + x0c;
    Pi[grp][lane][1] = base + y0c * W + x1c;
    Pi[grp][lane][2] = base + y1c * W + x0c;
    Pi[grp][lane][3] = base + y1c * W + x1c;
    Pw[grp][lane][0] = (1.f - wx) * (1.f - wy) * vx0 * vy0 * a;
    Pw[grp][lane][1] = wx * (1.f - wy) * vx1 * vy0 * a;
    Pw[grp][lane][2] = (1.f - wx) * wy * vx0 * vy1 * a;
    Pw[grp][lane][3] = wx * wy * vx1 * vy1 * a;

    const ushort* vb = valt + (size_t)(b * 8 + h) * (LENS * 32);
    float accx = 0.f, accy = 0.f;
#pragma unroll 4
    for (int s = 0; s < 16; ++s) {
        int4  idx = *reinterpret_cast<const int4*>(Pi[grp][s]);
        float4 w  = *reinterpret_cast<const float4*>(Pw[grp][s]);
        uint32_t u00 = *reinterpret_cast<const uint32_t*>(vb + idx.x * 32 + lane * 2);
        uint32_t u10 = *reinterpret_cast<const uint32_t*>(vb + idx.y * 32 + lane * 2);
        uint32_t u01 = *reinterpret_cast<const uint32_t*>(vb + idx.z * 32 + lane * 2);
        uint32_t u11 = *reinterpret_cast<const uint32_t*>(vb + idx.w * 32 + lane * 2);
        accx = fmaf(w.x, b2f_lo(u00), accx); accy = fmaf(w.x, b2f_hi(u00), accy);
        accx = fmaf(w.y, b2f_lo(u10), accx); accy = fmaf(w.y, b2f_hi(u10), accy);
        accx = fmaf(w.z, b2f_lo(u01), accx); accy = fmaf(w.z, b2f_hi(u01), accy);
        accx = fmaf(w.w, b2f_lo(u11), accx); accy = fmaf(w.w, b2f_hi(u11), accy);
    }
    uint32_t pack = ((uint32_t)f2b(accy) << 16) | (uint32_t)f2b(accx);
    *reinterpret_cast<uint32_t*>(out + (size_t)bq * 256 + h * 32 + lane * 2) = pack;
}

// ---------------------------------------------------------------------------
// Fused residual + LayerNorm; optional bf16 copy and bf16(x+qpos) output.
// ---------------------------------------------------------------------------
__global__ __launch_bounds__(256) void ln_kernel(
    const float* __restrict__ x, const float* __restrict__ y,
    const float* __restrict__ g, const float* __restrict__ beta,
    float* __restrict__ out, ushort* __restrict__ out_bf,
    const float* __restrict__ qpos, ushort* __restrict__ qadd_bf)
{
    const int r = blockIdx.x;
    const int c = threadIdx.x;
    float v = x[(size_t)r * 256 + c] + y[(size_t)r * 256 + c];
    float s1 = v, s2 = v * v;
#pragma unroll
    for (int msk = 32; msk; msk >>= 1) {
        s1 += __shfl_xor(s1, msk);
        s2 += __shfl_xor(s2, msk);
    }
    __shared__ float red[8];
    int w = c >> 6;
    if ((c & 63) == 0) { red[w] = s1; red[4 + w] = s2; }
    __syncthreads();
    s1 = red[0] + red[1] + red[2] + red[3];
    s2 = red[4] + red[5] + red[6] + red[7];
    float mean = s1 * (1.f / 256.f);
    float var  = s2 * (1.f / 256.f) - mean * mean;
    float inv  = 1.f / sqrtf(var + 1e-5f);
    float o = (v - mean) * inv * g[c] + beta[c];
    out[(size_t)r * 256 + c] = o;
    if (out_bf) out_bf[(size_t)r * 256 + c] = f2b(o);
    if (qadd_bf) qadd_bf[(size_t)r * 256 + c] = f2b(o + qpos[(size_t)r * 256 + c]);
}

// ---------------------------------------------------------------------------
extern "C" void kernel_launch(void* const* d_in, const int* in_sizes, int n_in,
                              void* d_out, int out_size, void* d_ws, size_t ws_size,
                              hipStream_t stream)
{
    const float* tgt      = (const float*)d_in[0];
    const float* qpos     = (const float*)d_in[1];
    const float* refpts   = (const float*)d_in[2];
    const float* src      = (const float*)d_in[3];
    const unsigned char* padmask = (const unsigned char*)d_in[6];
    const float* sa_in_w  = (const float*)d_in[7];
    const float* sa_in_b  = (const float*)d_in[8];
    const float* sa_out_w = (const float*)d_in[9];
    const float* sa_out_b = (const float*)d_in[10];
    const float* ca_off_w = (const float*)d_in[11];
    const float* ca_off_b = (const float*)d_in[12];
    const float* ca_aw_w  = (const float*)d_in[13];
    const float* ca_aw_b  = (const float*)d_in[14];
    const float* ca_val_w = (const float*)d_in[15];
    const float* ca_val_b = (const float*)d_in[16];
    const float* ca_out_w = (const float*)d_in[17];
    const float* ca_out_b = (const float*)d_in[18];
    const float* n1_g     = (const float*)d_in[19];
    const float* n1_b     = (const float*)d_in[20];
    const float* n2_g     = (const float*)d_in[21];
    const float* n2_b     = (const float*)d_in[22];
    const float* n3_g     = (const float*)d_in[23];
    const float* n3_b     = (const float*)d_in[24];
    const float* f1_w     = (const float*)d_in[25];
    const float* f1_b     = (const float*)d_in[26];
    const float* f2_w     = (const float*)d_in[27];
    const float* f2_b     = (const float*)d_in[28];
    float* out = (float*)d_out;
    (void)in_sizes; (void)n_in; (void)out_size;

    float* ws = (float*)d_ws;
    size_t fo = 0;
    auto fa = [&](size_t n) { float* p = ws + fo; fo += n; return p; };
    float* buf_p   = fa((size_t)NQ * 256);
    float* t1      = fa((size_t)NQ * 256);
    float* t2      = fa((size_t)NQ * 256);
    float* offaw   = fa((size_t)NQ * 384);
    float* biascat = fa(384);
    fo = (fo + 3) & ~(size_t)3;
    ushort* ub = (ushort*)(ws + fo);
    size_t uo = 0;
    auto ua = [&](size_t n) { ushort* p = ub + uo; uo += n; return p; };
    ushort* w_bf    = ua(1015808);
    ushort* q_bf    = ua((size_t)NQ * 256);
    ushort* tgt_bf  = ua((size_t)NQ * 256);
    ushort* q2_bf   = ua((size_t)NQ * 256);
    ushort* qkv_bf  = ua((size_t)NQ * 768);
    ushort* attn_bf = ua((size_t)NQ * 256);
    ushort* dfo_bf  = ua((size_t)NQ * 256);
    ushort* t2_bf   = ua((size_t)NQ * 256);
    ushort* hid_bf  = ua((size_t)NQ * 1024);
    ushort* val_t   = ua((size_t)NV * 256);
    ushort* src_bf  = ua((size_t)NV * 256);     // only used if ws is big enough

    const size_t needed_bytes = fo * 4 + uo * 2;
    const bool use_cvt = ws_size >= needed_bytes;

    const ushort* w_sa_in  = w_bf + 0;
    const ushort* w_sa_out = w_bf + 196608;
    const ushort* w_offaw  = w_bf + 262144;
    const ushort* w_ca_val = w_bf + 360448;
    const ushort* w_ca_out = w_bf + 425984;
    const ushort* w_f1     = w_bf + 491520;
    const ushort* w_f2     = w_bf + 753664;

    dim3 blk(256);
    const int n4 = NQ * 256 / 4;

    WPtrs wp;
    wp.p[0] = sa_in_w; wp.p[1] = sa_out_w; wp.p[2] = ca_off_w; wp.p[3] = ca_aw_w;
    wp.p[4] = ca_val_w; wp.p[5] = ca_out_w; wp.p[6] = f1_w; wp.p[7] = f2_w;
    cvt_w_kernel<<<993, blk, 0, stream>>>(wp, w_bf, ca_off_b, ca_aw_b, biascat);

    // ---- self-attention ----
    cvt_pair_kernel<<<1800, blk, 0, stream>>>(tgt, qpos, q_bf, tgt_bf, n4);
    // fused QKV: bx<4 -> A=q_bf (q,k projections), bx>=4 -> A=tgt_bf (v projection)
    gemm_mfma<64, false, 1, false, false><<<dim3(6, 113), blk, 0, stream>>>(
        q_bf, tgt_bf, 4, w_sa_in, sa_in_b, qkv_bf, NQ, 256, 768, nullptr);
    attn_mfma<<<dim3(15, 8, 8), blk, 0, stream>>>(qkv_bf, attn_bf);
    gemm_mfma<64, false, 0, false, false><<<dim3(2, 113), blk, 0, stream>>>(
        attn_bf, nullptr, 0, w_sa_out, sa_out_b, buf_p, NQ, 256, 256, nullptr);
    ln_kernel<<<NQ, blk, 0, stream>>>(tgt, buf_p, n2_g, n2_b, t1, nullptr, qpos, q2_bf);

    // ---- deformable cross-attention ----
    if (use_cvt) {
        cvt_src_kernel<<<2720, blk, 0, stream>>>(src, src_bf, NV * 256 / 8);
        gemm_mfma<128, false, 2, false, true><<<dim3(2, 1360), blk, 0, stream>>>(
            src_bf, nullptr, 0, w_ca_val, ca_val_b, val_t, NV, 256, 256, padmask);
    } else {
        gemm_mfma<128, true, 2, false, true><<<dim3(2, 1360), blk, 0, stream>>>(
            src, nullptr, 0, w_ca_val, ca_val_b, val_t, NV, 256, 256, padmask);
    }
    gemm_mfma<64, false, 0, false, false><<<dim3(3, 113), blk, 0, stream>>>(
        q2_bf, nullptr, 0, w_offaw, biascat, offaw, NQ, 256, 384, nullptr);
    deform2_kernel<<<3600, blk, 0, stream>>>(val_t, offaw, refpts, dfo_bf);
    gemm_mfma<64, false, 0, false, false><<<dim3(2, 113), blk, 0, stream>>>(
        dfo_bf, nullptr, 0, w_ca_out, ca_out_b, buf_p, NQ, 256, 256, nullptr);
    ln_kernel<<<NQ, blk, 0, stream>>>(t1, buf_p, n1_g, n1_b, t2, t2_bf, nullptr, nullptr);

    // ---- FFN ----
    gemm_mfma<128, false, 1, true, false><<<dim3(8, 57), blk, 0, stream>>>(
        t2_bf, nullptr, 0, w_f1, f1_b, hid_bf, NQ, 256, 1024, nullptr);
    gemm_mfma<64, false, 0, false, false><<<dim3(2, 113), blk, 0, stream>>>(
        hid_bf, nullptr, 0, w_f2, f2_b, buf_p, NQ, 1024, 256, nullptr);
    ln_kernel<<<NQ, blk, 0, stream>>>(t2, buf_p, n3_g, n3_b, out, nullptr, nullptr, nullptr);
}